// Round 20
// baseline (662.665 us; speedup 1.0000x reference)
//
#include <hip/hip_runtime.h>
#include <cstdint>
#include <cstddef>

// Model dims
constexpr int TT   = 64;    // T
constexpr int DD   = 512;   // D
constexpr int NHEAD= 8;
constexpr int DHH  = 64;
constexpr int NPIX = 196;   // 14*14
constexpr int CIN  = 768;
constexpr int KSEL = 44;    // int(0.7*64)
constexpr int NG_FM= 784;   // B*N
constexpr int NIMG = 256;   // B*T
// distance_adj underflow band: exp(-|0.6*d^2+0.2|) in fp32.
// d=12 -> 2.4e-38 (normal). d=13 -> subnormal -> flushed (FTZ). d>=14 -> 0.
constexpr int DBAND = 12;

typedef __attribute__((ext_vector_type(8))) short bf16x8;
typedef __attribute__((ext_vector_type(4))) float f32x4;

__device__ __forceinline__ short bfr(float x) {
  union { float f; unsigned u; } v; v.f = x;
  unsigned r = (v.u + 0x7fffu + ((v.u >> 16) & 1u)) >> 16;   // RNE
  return (short)r;
}
__device__ __forceinline__ float bf2f(short s) {
  return __uint_as_float(((unsigned)(unsigned short)s) << 16);
}

// ---------------------------------------------------------------------------
// prep: pre_w (f32 [o][k], k=768) -> bf16 hi/lo in MFMA FRAGMENT order.
// ---------------------------------------------------------------------------
__global__ void k_prepPW2(const float* __restrict__ pw, short* __restrict__ hi,
                          short* __restrict__ lo)
{
  int m = blockIdx.x * 256 + threadIdx.x;            // < 512*96
  int o = m / 96, kc = m - o * 96;
  int mt = o >> 6, ot = (o >> 4) & 3, lr = o & 15;
  int ks = kc >> 2, lg = kc & 3;
  size_t addr = ((((size_t)(mt * 4 + ot) * 24 + ks) * 64 + lg * 16 + lr)) * 8;
  const float* src = pw + (size_t)o * CIN + kc * 8;
  #pragma unroll
  for (int j = 0; j < 8; j++) {
    float x = src[j];
    unsigned u = __float_as_uint(x);
    hi[addr + j] = (short)(u >> 16);
    lo[addr + j] = bfr(x - __uint_as_float(u & 0xffff0000u));
  }
}

// ---------------------------------------------------------------------------
// prep: fmap [n][c][hw] f32 -> bf16 hi/lo FRAGMENT order (half-batch).
// ---------------------------------------------------------------------------
__global__ __launch_bounds__(256) void k_prepFM3(
    const float* __restrict__ fmap, short* __restrict__ fh,
    short* __restrict__ fl, int n0)
{
  __shared__ float ar[64][197];                      // pitch 197
  const int cc = blockIdx.x;                         // 12 chunks of 64 ch
  const int nl = blockIdx.y;                         // 0..127
  const int tid = threadIdx.x;
  const float* src = fmap + ((size_t)(n0 + nl) * CIN + cc * 64) * NPIX;
  for (int i = tid; i < 64 * 49; i += 256) {
    int c = i / 49, q = i - c * 49;
    float4 v = *(const float4*)&src[(size_t)c * NPIX + q * 4];
    *(float4*)&ar[c][q * 4] = v;
  }
  __syncthreads();
  for (int i = tid; i < 208 * 8; i += 256) {
    int hw = i >> 3, kc = i & 7;
    int ks = cc * 2 + (kc >> 2), lg = kc & 3;
    size_t addr = ((((size_t)nl * 13 + (hw >> 4)) * 24 + ks) * 64 + lg * 16 + (hw & 15)) * 8;
    union { short s[8]; bf16x8 v; } hh, ll;
    #pragma unroll
    for (int j = 0; j < 8; j++) {
      float x = (hw < NPIX) ? ar[kc * 8 + j][hw] : 0.f;
      unsigned u = __float_as_uint(x);
      hh.s[j] = (short)(u >> 16);
      ll.s[j] = bfr(x - __uint_as_float(u & 0xffff0000u));
    }
    *(bf16x8*)&fh[addr] = hh.v;
    *(bf16x8*)&fl[addr] = ll.v;
  }
}

// ---------------------------------------------------------------------------
// K1: pre head 1x1 conv (768->512) + bias + ReLU via split-bf16 MFMA.
// B (fm) fragments prefetched ONE K-step ahead into a register ping-pong.
// ---------------------------------------------------------------------------
__global__ __launch_bounds__(256) void k_preconv3(
    const short* __restrict__ fmfh, const short* __restrict__ fmfl,
    const short* __restrict__ pwfh, const short* __restrict__ pwfl,
    const float* __restrict__ pb, short* __restrict__ axb,
    double* __restrict__ sums, int n0)
{
  __shared__ float arena[7616];                      // epilogue only
  const int wg = blockIdx.x;                         // 1024 (128 imgs)
  const int mt = (wg >> 3) & 7;                      // o-chunk
  const int nl = (wg & 7) | ((wg >> 6) << 3);        // local image (XCD-group)
  const int n  = n0 + nl;
  const int b  = n >> 6, t = n & 63;
  const int tid = threadIdx.x;
  const int w = tid >> 6, l = tid & 63;
  const int lr = l & 15, lg = l >> 4;
  const int o0 = mt * 64;

  const int hwt0 = (w == 0) ? 0 : 1 + 3 * w;         // waves: 4,3,3,3 hw-tiles
  const int nq   = (w == 0) ? 4 : 3;

  const short* fbh = fmfh + ((size_t)nl * 13 + hwt0) * 12288 + l * 8;
  const short* fbl = fmfl + ((size_t)nl * 13 + hwt0) * 12288 + l * 8;
  const short* pwh = pwfh + (size_t)(mt * 4) * 12288 + l * 8;
  const short* pwl = pwfl + (size_t)(mt * 4) * 12288 + l * 8;

  f32x4 acc[4][4];                                   // [q][ot]
  #pragma unroll
  for (int q = 0; q < 4; q++)
    #pragma unroll
    for (int ot = 0; ot < 4; ot++) acc[q][ot] = (f32x4){0.f, 0.f, 0.f, 0.f};

  bf16x8 BhA[4], BlA[4], BhB[4], BlB[4];
  #pragma unroll
  for (int q = 0; q < 4; q++) if (q < nq) {          // preload ks=0 -> set A
    BhA[q] = *(const bf16x8*)&fbh[(size_t)q * 12288];
    BlA[q] = *(const bf16x8*)&fbl[(size_t)q * 12288];
  }

  for (int kp = 0; kp < 12; kp++) {
    const int ks0 = kp * 2;
    #pragma unroll
    for (int q = 0; q < 4; q++) if (q < nq) {
      BhB[q] = *(const bf16x8*)&fbh[(size_t)q * 12288 + (ks0 + 1) * 512];
      BlB[q] = *(const bf16x8*)&fbl[(size_t)q * 12288 + (ks0 + 1) * 512];
    }
    {
      bf16x8 Ah[4], Al[4];
      #pragma unroll
      for (int ot = 0; ot < 4; ot++) {
        Ah[ot] = *(const bf16x8*)&pwh[(size_t)ot * 12288 + ks0 * 512];
        Al[ot] = *(const bf16x8*)&pwl[(size_t)ot * 12288 + ks0 * 512];
      }
      #pragma unroll
      for (int q = 0; q < 4; q++) if (q < nq) {
        #pragma unroll
        for (int ot = 0; ot < 4; ot++) {
          acc[q][ot] = __builtin_amdgcn_mfma_f32_16x16x32_bf16(Al[ot], BhA[q], acc[q][ot], 0, 0, 0);
          acc[q][ot] = __builtin_amdgcn_mfma_f32_16x16x32_bf16(Ah[ot], BlA[q], acc[q][ot], 0, 0, 0);
          acc[q][ot] = __builtin_amdgcn_mfma_f32_16x16x32_bf16(Ah[ot], BhA[q], acc[q][ot], 0, 0, 0);
        }
      }
    }
    if (kp < 11) {
      #pragma unroll
      for (int q = 0; q < 4; q++) if (q < nq) {
        BhA[q] = *(const bf16x8*)&fbh[(size_t)q * 12288 + (ks0 + 2) * 512];
        BlA[q] = *(const bf16x8*)&fbl[(size_t)q * 12288 + (ks0 + 2) * 512];
      }
    }
    {
      bf16x8 Ah[4], Al[4];
      #pragma unroll
      for (int ot = 0; ot < 4; ot++) {
        Ah[ot] = *(const bf16x8*)&pwh[(size_t)ot * 12288 + (ks0 + 1) * 512];
        Al[ot] = *(const bf16x8*)&pwl[(size_t)ot * 12288 + (ks0 + 1) * 512];
      }
      #pragma unroll
      for (int q = 0; q < 4; q++) if (q < nq) {
        #pragma unroll
        for (int ot = 0; ot < 4; ot++) {
          acc[q][ot] = __builtin_amdgcn_mfma_f32_16x16x32_bf16(Al[ot], BhB[q], acc[q][ot], 0, 0, 0);
          acc[q][ot] = __builtin_amdgcn_mfma_f32_16x16x32_bf16(Ah[ot], BlB[q], acc[q][ot], 0, 0, 0);
          acc[q][ot] = __builtin_amdgcn_mfma_f32_16x16x32_bf16(Ah[ot], BhB[q], acc[q][ot], 0, 0, 0);
        }
      }
    }
  }

  float4 pbf[4];
  #pragma unroll
  for (int ot = 0; ot < 4; ot++)
    pbf[ot] = *(const float4*)&pb[o0 + ot * 16 + 4 * lg];

  #pragma unroll
  for (int pass = 0; pass < 2; pass++) {
    const int tbase = pass ? 7 : 0;
    const int tend  = pass ? 13 : 7;
    const int rbase = tbase * 16;
    const int rows  = (tend - tbase) * 16;
    __syncthreads();
    #pragma unroll
    for (int q = 0; q < 4; q++) if (q < nq) {
      int hwt = hwt0 + q;
      if (hwt >= tbase && hwt < tend) {
        int row_l = hwt * 16 + lr - rbase;
        #pragma unroll
        for (int ot = 0; ot < 4; ot++) {
          int col = (ot * 16 + 4 * lg + 4 * row_l) % 68;   // skew: conflict-free
          f32x4 a = acc[q][ot];
          float4 o4v;
          o4v.x = fmaxf(a[0] + pbf[ot].x, 0.f);
          o4v.y = fmaxf(a[1] + pbf[ot].y, 0.f);
          o4v.z = fmaxf(a[2] + pbf[ot].z, 0.f);
          o4v.w = fmaxf(a[3] + pbf[ot].w, 0.f);
          *(float4*)&arena[row_l * 68 + col] = o4v;
        }
      }
    }
    __syncthreads();
    for (int i = tid; i < rows * 16; i += 256) {      // trip uniform
      int row_l = i >> 4, o4 = i & 15;
      int hw = rbase + row_l;
      float4 v = make_float4(0.f, 0.f, 0.f, 0.f);
      if (hw < NPIX) {
        int col = (o4 * 4 + 4 * row_l) % 68;
        v = *(const float4*)&arena[row_l * 68 + col];
        size_t idx = ((size_t)(b * NPIX + hw) * TT + t) * DD + o0 + o4 * 4;
        *(short4*)&axb[idx] = make_short4(bfr(v.x), bfr(v.y), bfr(v.z), bfr(v.w));
      }
      double vs = (double)v.x * v.x + (double)v.y * v.y
                + (double)v.z * v.z + (double)v.w * v.w;
      vs += __shfl_xor(vs, 1); vs += __shfl_xor(vs, 2);
      vs += __shfl_xor(vs, 4); vs += __shfl_xor(vs, 8);
      if ((i & 15) == 0 && hw < NPIX)
        atomicAdd(&sums[(size_t)(b * NPIX + hw) * TT + t], vs);
    }
  }
}

// ---------------------------------------------------------------------------
// GEMM B-operand preps -> bf16 FRAGMENT order.
// ---------------------------------------------------------------------------
__global__ void k_prepWb2(const float* __restrict__ W, short* __restrict__ o)
{
  int m = blockIdx.x * 256 + threadIdx.x;            // < 512*64
  int j = m >> 6, kc = m & 63;
  int ks = kc >> 2, lg = kc & 3;
  size_t addr = (((size_t)(j >> 4) * 16 + ks) * 64 + lg * 16 + (j & 15)) * 8;
  #pragma unroll
  for (int jj = 0; jj < 8; jj++) {
    int k = kc * 8 + jj;
    o[addr + jj] = bfr(W[(size_t)(j >> 6) * (DD * DHH) + (size_t)k * DHH + (j & 63)]);
  }
}

__global__ void k_prepLWb2(const float* __restrict__ a, short* __restrict__ o)
{
  int m = blockIdx.x * 256 + threadIdx.x;            // < 512*64
  int j = m >> 6, kc = m & 63;
  int ks = kc >> 2, lg = kc & 3;
  size_t addr = (((size_t)(j >> 4) * 16 + ks) * 64 + lg * 16 + (j & 15)) * 8;
  const float* src = a + (size_t)j * DD + kc * 8;
  #pragma unroll
  for (int jj = 0; jj < 8; jj++) o[addr + jj] = bfr(src[jj]);
}

__global__ void k_cvt(const float* __restrict__ a, short* __restrict__ o)
{
  int m = blockIdx.x * 256 + threadIdx.x;
  o[m] = bfr(a[m]);
}

// gp = ln_g * post_w; cst[0] = sum(gp); cst[1] = sum(ln_b*post_w) + post_b
__global__ void k_prepGP(const float* __restrict__ g, const float* __restrict__ b,
                         const float* __restrict__ pw, const float* __restrict__ pb,
                         float* __restrict__ gp, float* __restrict__ cst)
{
  __shared__ float red[256], red2[256];
  int tid = threadIdx.x;
  float s1 = 0.f, s2 = 0.f;
  for (int c = tid; c < 512; c += 256) {
    float gpv = g[c] * pw[c];
    gp[c] = gpv;
    s1 += gpv;
    s2 += b[c] * pw[c];
  }
  red[tid] = s1; red2[tid] = s2;
  __syncthreads();
  for (int s = 128; s > 0; s >>= 1) {
    if (tid < s) { red[tid] += red[tid + s]; red2[tid] += red2[tid + s]; }
    __syncthreads();
  }
  if (tid == 0) { cst[0] = red[0]; cst[1] = red2[0] + pb[0]; }
}

// ---------------------------------------------------------------------------
// K2a/K2b: top-k selection bitmasks (fp64 ranking).
// ---------------------------------------------------------------------------
__global__ void k_topk(const float* __restrict__ x, unsigned long long* __restrict__ sel)
{
  int g = blockIdx.x, lane = threadIdx.x;            // 64 threads
  const float* row = x + ((size_t)g * TT + lane) * DD;
  double s = 0.0;
  for (int dd = 0; dd < DD; dd += 4) {
    float4 v = *(const float4*)(row + dd);
    s += (double)v.x * (double)v.x + (double)v.y * (double)v.y
       + (double)v.z * (double)v.z + (double)v.w * (double)v.w;
  }
  __shared__ double mag[64];
  mag[lane] = s;
  __syncthreads();
  int rank = 0;
  for (int j = 0; j < 64; j++) {
    double m = mag[j];
    rank += (m > s) || (m == s && j < lane);
  }
  unsigned long long bal = __ballot(rank < KSEL);
  if (lane == 0) sel[g] = bal;
}

__global__ void k_topk2(const double* __restrict__ sums, unsigned long long* __restrict__ sel)
{
  int g = blockIdx.x, lane = threadIdx.x;
  double s = sums[(size_t)g * TT + lane];
  __shared__ double mag[64];
  mag[lane] = s;
  __syncthreads();
  int rank = 0;
  for (int j = 0; j < 64; j++) {
    double m = mag[j];
    rank += (m > s) || (m == s && j < lane);
  }
  unsigned long long bal = __ballot(rank < KSEL);
  if (lane == 0) sel[g] = bal;
}

// ---------------------------------------------------------------------------
// K3a-TM: flat GEMM (round-10/13 proven structure) for tiny TM launches.
// ---------------------------------------------------------------------------
__global__ __launch_bounds__(256) void k_gemm(
    const short* __restrict__ Ab, const short* __restrict__ Bbf,
    const float* __restrict__ bias, const float* __restrict__ Res,
    float* __restrict__ Outf, short* __restrict__ Outb,
    int Mtiles, int swz)
{
  __shared__ short Asl[2][128 * 40];
  const int wg = blockIdx.x;
  int mt, nt;
  if (swz) { int xcd = wg & 7, idx = wg >> 3; mt = xcd * (Mtiles >> 3) + (idx >> 2); nt = idx & 3; }
  else     { mt = wg >> 2; nt = wg & 3; }
  const int m0 = mt * 128, n0 = nt * 128;
  const int tid = threadIdx.x;
  const int l  = tid & 63;
  const int lr = l & 15, lg = l >> 4;
  const int wm = (tid >> 7) & 1, wn = (tid >> 6) & 1;

  const int srow = tid >> 1, skq = tid & 1;
  const short* gA = Ab + (size_t)(m0 + srow) * DD + skq * 16;
  const int soff = srow * 40 + skq * 16;

  bf16x8 ra0 = *(const bf16x8*)(gA);
  bf16x8 ra1 = *(const bf16x8*)(gA + 8);
  *(bf16x8*)&Asl[0][soff]     = ra0;
  *(bf16x8*)&Asl[0][soff + 8] = ra1;
  __syncthreads();

  f32x4 acc[4][4] = {};
  for (int ks = 0; ks < 16; ks++) {
    const int cur = ks & 1;
    if (ks < 15) {
      const int k0 = (ks + 1) * 32;
      ra0 = *(const bf16x8*)(gA + k0);
      ra1 = *(const bf16x8*)(gA + k0 + 8);
    }
    bf16x8 af[4], bfv[4];
    #pragma unroll
    for (int mi = 0; mi < 4; mi++)
      af[mi] = *(const bf16x8*)&Asl[cur][(wm * 64 + mi * 16 + lr) * 40 + lg * 8];
    #pragma unroll
    for (int ni = 0; ni < 4; ni++) {
      size_t boff = (((size_t)(nt * 8 + wn * 4 + ni) * 16 + ks) * 64 + l) * 8;
      bfv[ni] = *(const bf16x8*)&Bbf[boff];
    }
    #pragma unroll
    for (int mi = 0; mi < 4; mi++)
      #pragma unroll
      for (int ni = 0; ni < 4; ni++)
        acc[mi][ni] = __builtin_amdgcn_mfma_f32_16x16x32_bf16(af[mi], bfv[ni], acc[mi][ni], 0, 0, 0);
    if (ks < 15) {
      *(bf16x8*)&Asl[cur ^ 1][soff]     = ra0;
      *(bf16x8*)&Asl[cur ^ 1][soff + 8] = ra1;
      __syncthreads();
    }
  }

  #pragma unroll
  for (int mi = 0; mi < 4; mi++) {
    #pragma unroll
    for (int r = 0; r < 4; r++) {
      const size_t row = (size_t)(m0 + wm * 64 + mi * 16 + lg * 4 + r);
      #pragma unroll
      for (int ni = 0; ni < 4; ni++) {
        const int col = n0 + wn * 64 + ni * 16 + lr;
        float v = acc[mi][ni][r];
        if (bias) v += bias[col];
        if (Res)  v += Res[row * DD + col];
        if (Outf) Outf[row * DD + col] = v;
        if (Outb) Outb[row * DD + col] = bfr(v);
      }
    }
  }
}

// ---------------------------------------------------------------------------
// K3a-FM: gemm1 on the gemm2ln structure: block-per-half-graph (32 rows),
// A staged ONCE (no main-loop barriers), B fragment-direct from L2, acc 16
// f32x4; output restaged through A-LDS for coalesced bf16x8 stores.
// ---------------------------------------------------------------------------
__global__ __launch_bounds__(256) void k_gemm1g(
    const short* __restrict__ Ab, const short* __restrict__ Bbf,
    short* __restrict__ Outb)
{
  __shared__ short Asl[32 * 520];                    // 33,280 B
  const int wg = blockIdx.x;                         // 1568
  const int xcd = wg & 7, idx = wg >> 3;             // idx 0..195
  const int g = xcd * 98 + (idx >> 1);               // graph (XCD-grouped)
  const int half = idx & 1;
  const int m0 = g * 64 + half * 32;
  const int tid = threadIdx.x;
  const int w = tid >> 6, l = tid & 63;
  const int lr = l & 15, lg = l >> 4;
  const int rowb = (w & 1) * 16;
  const int ntb = (w >> 1) * 16;                     // col half

  // stage A: 32 rows x 512 shorts, fully coalesced
  #pragma unroll
  for (int i = 0; i < 8; i++) {
    int c = tid + i * 256;                           // < 2048 chunks of 8
    int row = c >> 6, off = (c & 63) * 8;
    *(bf16x8*)&Asl[row * 520 + off] =
        *(const bf16x8*)&Ab[(size_t)(m0 + row) * DD + off];
  }
  __syncthreads();

  f32x4 acc[16];
  #pragma unroll
  for (int i = 0; i < 16; i++) acc[i] = (f32x4){0.f, 0.f, 0.f, 0.f};

  for (int ks = 0; ks < 16; ks++) {
    bf16x8 af = *(const bf16x8*)&Asl[(rowb + lr) * 520 + ks * 32 + lg * 8];
    #pragma unroll
    for (int ntl = 0; ntl < 16; ntl++) {
      bf16x8 bb = *(const bf16x8*)&Bbf[(((size_t)(ntb + ntl) * 16 + ks) * 64 + l) * 8];
      acc[ntl] = __builtin_amdgcn_mfma_f32_16x16x32_bf16(af, bb, acc[ntl], 0, 0, 0);
    }
  }

  // restage output through A-LDS (reads complete) for coalesced stores
  __syncthreads();
  #pragma unroll
  for (int ntl = 0; ntl < 16; ntl++)
    #pragma unroll
    for (int r = 0; r < 4; r++)
      Asl[(rowb + lg * 4 + r) * 520 + (ntb + ntl) * 16 + lr] = bfr(acc[ntl][r]);
  __syncthreads();
  #pragma unroll
  for (int i = 0; i < 8; i++) {
    int c = tid + i * 256;
    int row = c >> 6, off = (c & 63) * 8;
    *(bf16x8*)&Outb[(size_t)(m0 + row) * DD + off] =
        *(const bf16x8*)&Asl[row * 520 + off];
  }
}

// ---------------------------------------------------------------------------
// K4-FM: FUSED gemm2 + LayerNorm + post-conv (round-17: 2 blocks/graph).
// ---------------------------------------------------------------------------
__global__ __launch_bounds__(256) void k_gemm2ln(
    const short* __restrict__ Ab, const short* __restrict__ Bbf,
    const float* __restrict__ bias, const short* __restrict__ Resb,
    const float* __restrict__ gp, const float* __restrict__ cst,
    float* __restrict__ outp)
{
  __shared__ short Asl[32 * 520];                    // 33,280 B
  __shared__ float red[2][32][3];                    // 768 B
  const int wg = blockIdx.x;                         // 1568
  const int xcd = wg & 7, idx = wg >> 3;             // idx 0..195
  const int g = xcd * 98 + (idx >> 1);               // graph (XCD-grouped)
  const int half = idx & 1;
  const int m0 = g * 64 + half * 32;
  const int tid = threadIdx.x;
  const int w = tid >> 6, l = tid & 63;
  const int lr = l & 15, lg = l >> 4;
  const int rowb = (w & 1) * 16;
  const int ch  = w >> 1;                            // col half
  const int ntb = ch * 16;

  #pragma unroll
  for (int i = 0; i < 8; i++) {
    int c = tid + i * 256;                           // < 2048 chunks of 8
    int row = c >> 6, off = (c & 63) * 8;
    *(bf16x8*)&Asl[row * 520 + off] =
        *(const bf16x8*)&Ab[(size_t)(m0 + row) * DD + off];
  }
  __syncthreads();

  f32x4 acc[16];
  #pragma unroll
  for (int i = 0; i < 16; i++) acc[i] = (f32x4){0.f, 0.f, 0.f, 0.f};

  for (int ks = 0; ks < 16; ks++) {
    bf16x8 af = *(const bf16x8*)&Asl[(rowb + lr) * 520 + ks * 32 + lg * 8];
    #pragma unroll
    for (int ntl = 0; ntl < 16; ntl++) {
      bf16x8 bb = *(const bf16x8*)&Bbf[(((size_t)(ntb + ntl) * 16 + ks) * 64 + l) * 8];
      acc[ntl] = __builtin_amdgcn_mfma_f32_16x16x32_bf16(af, bb, acc[ntl], 0, 0, 0);
    }
  }

  float sum[4] = {0.f,0.f,0.f,0.f}, sumsq[4] = {0.f,0.f,0.f,0.f}, dgp[4] = {0.f,0.f,0.f,0.f};
  #pragma unroll
  for (int ntl = 0; ntl < 16; ntl++) {
    int col = (ntb + ntl) * 16 + lr;
    float bi  = bias[col];
    float gpv = gp[col];
    #pragma unroll
    for (int r = 0; r < 4; r++) {
      size_t row = (size_t)(m0 + rowb + lg * 4 + r);
      float v = acc[ntl][r] + bi + bf2f(Resb[row * DD + col]);
      sum[r] += v; sumsq[r] += v * v; dgp[r] += v * gpv;
    }
  }
  #pragma unroll
  for (int r = 0; r < 4; r++) {
    #pragma unroll
    for (int mof = 1; mof <= 8; mof <<= 1) {
      sum[r]   += __shfl_xor(sum[r], mof);
      sumsq[r] += __shfl_xor(sumsq[r], mof);
      dgp[r]   += __shfl_xor(dgp[r], mof);
    }
    if (lr == 0) {
      int rl = rowb + lg * 4 + r;                    // 0..31
      red[ch][rl][0] = sum[r]; red[ch][rl][1] = sumsq[r]; red[ch][rl][2] = dgp[r];
    }
  }
  __syncthreads();
  if (tid < 32) {
    float S = red[0][tid][0] + red[1][tid][0];
    float Q = red[0][tid][1] + red[1][tid][1];
    float D = red[0][tid][2] + red[1][tid][2];
    float mean = S * (1.f / 512.f);
    float var  = Q * (1.f / 512.f) - mean * mean;
    float rstd = rsqrtf(var + 1e-5f);
    const int b = g / NPIX, hw = g - b * NPIX;
    const int t = half * 32 + tid;
    outp[(size_t)b * (TT * NPIX) + t * NPIX + hw] = rstd * (D - mean * cst[0]) + cst[1];
  }
}

// ---------------------------------------------------------------------------
// K3b: fused GAT attention per (head, graph); h bf16 row-major, in-place.
// PV product via MFMA (round-18 structure).
// ---------------------------------------------------------------------------
__global__ __launch_bounds__(256) void k_attn(
    short* __restrict__ tmp, const float* __restrict__ a1v,
    const float* __restrict__ a2v, const unsigned long long* __restrict__ sel)
{
  __shared__ short hb[4096];                         // B-frags: [ct*2+ks][64][8]
  __shared__ short attnb[64 * 72];                   // A-frags: P bf16, pitch 72
  __shared__ float s1[64], s2[64], aw[128], cnorm[64];
  __shared__ float redc[4][4][16];                   // [wave][ct][lr]
  const int h = blockIdx.x, g = blockIdx.y;
  const int tid = threadIdx.x;
  const int w = tid >> 6, l = tid & 63;
  const int lr = l & 15, lg = l >> 4;
  short* base = tmp + (size_t)g * TT * DD + h * DHH;

  if (tid < 128) aw[tid] = (tid < 64) ? a1v[h * 64 + tid] : a2v[h * 64 + (tid - 64)];
  __syncthreads();

  #pragma unroll
  for (int p = 0; p < 2; p++) {
    int c = tid + p * 256;                           // 0..511
    int t = c >> 3, k8 = c & 7;                      // row t, col chunk
    bf16x8 v = *(const bf16x8*)&base[(size_t)t * DD + k8 * 8];
    const int ct = k8 >> 1;                          // col tile
    const int ks = t >> 5, lgk = (t >> 3) & 3, jj = t & 7;
    const int cbase = ((ct * 2 + ks) * 64 + lgk * 16 + (k8 & 1) * 8) * 8 + jj;
    float v1 = 0.f, v2 = 0.f;
    #pragma unroll
    for (int j = 0; j < 8; j++) {
      float x = bf2f(v[j]);
      int dh = k8 * 8 + j;
      v1 += x * aw[dh];
      v2 += x * aw[64 + dh];
      hb[cbase + j * 8] = v[j];
    }
    v1 += __shfl_xor(v1, 1); v1 += __shfl_xor(v1, 2); v1 += __shfl_xor(v1, 4);
    v2 += __shfl_xor(v2, 1); v2 += __shfl_xor(v2, 2); v2 += __shfl_xor(v2, 4);
    if (k8 == 0) { s1[t] = v1; s2[t] = v2; }
  }
  __syncthreads();

  const unsigned long long sm = sel[g];
  {
    const int i4 = tid >> 2, sub = tid & 3;
    const bool seli = (sm >> i4) & 1ULL;
    const float vi = s1[i4];
    float ev[16];
    float mx = -1e30f;
    #pragma unroll
    for (int q = 0; q < 16; q++) {
      int j = sub * 16 + q;
      float e = vi + s2[j];
      e = e >= 0.f ? e : 0.2f * e;                   // leaky_relu(0.2)
      int dist = i4 > j ? i4 - j : j - i4;
      bool ok = (seli || ((sm >> j) & 1ULL)) && (dist <= DBAND);
      e = ok ? e : -9e15f;
      ev[q] = e;
      mx = fmaxf(mx, e);
    }
    mx = fmaxf(mx, __shfl_xor(mx, 1));
    mx = fmaxf(mx, __shfl_xor(mx, 2));
    float sum = 0.f;
    #pragma unroll
    for (int q = 0; q < 16; q++) { ev[q] = expf(ev[q] - mx); sum += ev[q]; }
    sum += __shfl_xor(sum, 1); sum += __shfl_xor(sum, 2);
    float inv = 1.f / sum;
    #pragma unroll
    for (int q = 0; q < 16; q++)
      attnb[i4 * 72 + sub * 16 + q] = bfr(ev[q] * inv);
  }
  __syncthreads();

  f32x4 acc[4];
  #pragma unroll
  for (int ct = 0; ct < 4; ct++) acc[ct] = (f32x4){0.f, 0.f, 0.f, 0.f};
  #pragma unroll
  for (int ks = 0; ks < 2; ks++) {
    bf16x8 af = *(const bf16x8*)&attnb[(w * 16 + lr) * 72 + ks * 32 + lg * 8];
    #pragma unroll
    for (int ct = 0; ct < 4; ct++) {
      bf16x8 bb = *(const bf16x8*)&hb[((ct * 2 + ks) * 64 + l) * 8];
      acc[ct] = __builtin_amdgcn_mfma_f32_16x16x32_bf16(af, bb, acc[ct], 0, 0, 0);
    }
  }

  float vv[4][4];
  float cs[4] = {0.f, 0.f, 0.f, 0.f};
  #pragma unroll
  for (int ct = 0; ct < 4; ct++)
    #pragma unroll
    for (int r = 0; r < 4; r++) {
      float v = acc[ct][r];
      v = v > 0.f ? v : expm1f(v);
      v = v >= 0.f ? sqrtf(v) : -sqrtf(-v);
      vv[ct][r] = v;
      cs[ct] += v * v;
    }
  #pragma unroll
  for (int ct = 0; ct < 4; ct++) {
    cs[ct] += __shfl_xor(cs[ct], 16);
    cs[ct] += __shfl_xor(cs[ct], 32);
    if (lg == 0) redc[w][ct][lr] = cs[ct];
  }
  __syncthreads();
  if (tid < 64) {
    int ct = tid >> 4, c = tid & 15;
    float S = redc[0][ct][c] + redc[1][ct][c] + redc[2][ct][c] + redc[3][ct][c];
    cnorm[ct * 16 + c] = fmaxf(sqrtf(S), 1e-12f);
  }
  __syncthreads();
  #pragma unroll
  for (int ct = 0; ct < 4; ct++) {
    float inv = 1.f / cnorm[ct * 16 + lr];
    #pragma unroll
    for (int r = 0; r < 4; r++)
      attnb[(w * 16 + lg * 4 + r) * 72 + ct * 16 + lr] = bfr(vv[ct][r] * inv);
  }
  __syncthreads();
  #pragma unroll
  for (int p = 0; p < 2; p++) {
    int c = tid + p * 256;
    int t = c >> 3, k8 = c & 7;
    *(bf16x8*)&base[(size_t)t * DD + k8 * 8] =
        *(const bf16x8*)&attnb[t * 72 + k8 * 8];
  }
}

// ---------------------------------------------------------------------------
// K5: LayerNorm in-place (TM path), one wave per 512-row.
// ---------------------------------------------------------------------------
__global__ void k_ln(float* __restrict__ x, const float* __restrict__ gam, const float* __restrict__ bet)
{
  const size_t row = blockIdx.x;
  const int lane = threadIdx.x;
  float* p = x + row * DD + lane * 8;
  float4 v0 = *(float4*)p;
  float4 v1 = *(float4*)(p + 4);
  float va[8] = {v0.x, v0.y, v0.z, v0.w, v1.x, v1.y, v1.z, v1.w};
  float s = 0.f;
  #pragma unroll
  for (int i = 0; i < 8; i++) s += va[i];
  #pragma unroll
  for (int m = 32; m >= 1; m >>= 1) s += __shfl_xor(s, m);
  float mean = s * (1.f / 512.f);
  float q = 0.f;
  #pragma unroll
  for (int i = 0; i < 8; i++) { float d = va[i] - mean; q += d * d; }
  #pragma unroll
  for (int m = 32; m >= 1; m >>= 1) q += __shfl_xor(q, m);
  float rstd = rsqrtf(q * (1.f / 512.f) + 1e-5f);
  const float* gp = gam + lane * 8;
  const float* bp = bet + lane * 8;
  float4 g0 = *(const float4*)gp, g1 = *(const float4*)(gp + 4);
  float4 b0 = *(const float4*)bp, b1 = *(const float4*)(bp + 4);
  float ga[8] = {g0.x, g0.y, g0.z, g0.w, g1.x, g1.y, g1.z, g1.w};
  float ba[8] = {b0.x, b0.y, b0.z, b0.w, b1.x, b1.y, b1.z, b1.w};
  float o[8];
  #pragma unroll
  for (int i = 0; i < 8; i++) o[i] = (va[i] - mean) * rstd * ga[i] + ba[i];
  *(float4*)p       = make_float4(o[0], o[1], o[2], o[3]);
  *(float4*)(p + 4) = make_float4(o[4], o[5], o[6], o[7]);
}

// ---------------------------------------------------------------------------
// K7: classifier Conv1d(512->512)+GELU(exact)+Conv1d(512->1), one block per (b,t).
// ---------------------------------------------------------------------------
__global__ __launch_bounds__(256) void k_cls(
    const float* __restrict__ xv, const float* __restrict__ w1,
    const float* __restrict__ b1, const float* __restrict__ w2,
    const float* __restrict__ b2, float* __restrict__ outp)
{
  const int m = blockIdx.x;                          // b*64+t
  const int tid = threadIdx.x;
  __shared__ float xr[512];
  __shared__ float red[256];
  xr[tid] = xv[(size_t)m * DD + tid];
  xr[tid + 256] = xv[(size_t)m * DD + tid + 256];
  __syncthreads();
  float part = 0.f;
  for (int o = tid; o < 512; o += 256) {
    const float* wr = w1 + (size_t)o * DD;
    float d = 0.f;
    for (int cc = 0; cc < DD; cc += 4) {
      float4 wv = *(const float4*)(wr + cc);
      d += wv.x * xr[cc] + wv.y * xr[cc + 1] + wv.z * xr[cc + 2] + wv.w * xr[cc + 3];
    }
    d += b1[o];
    float ge = 0.5f * d * (1.0f + erff(d * 0.70710678118654752f));
    part += ge * w2[o];
  }
  red[tid] = part;
  __syncthreads();
  for (int s = 128; s > 0; s >>= 1) {
    if (tid < s) red[tid] += red[tid + s];
    __syncthreads();
  }
  if (tid == 0) outp[m] = red[0] + b2[0];
}

// ---------------------------------------------------------------------------
extern "C" void kernel_launch(void* const* d_in, const int* in_sizes, int n_in,
                              void* d_out, int out_size, void* d_ws, size_t ws_size,
                              hipStream_t stream)
{
  const float* x_v    = (const float*)d_in[0];
  const float* fmap   = (const float*)d_in[1];
  const float* pre_w  = (const float*)d_in[2];
  const float* pre_b  = (const float*)d_in[3];
  const float* post_w = (const float*)d_in[4];
  const float* post_b = (const float*)d_in[5];
  const float* tm_W   = (const float*)d_in[6];
  const float* tm_a1  = (const float*)d_in[7];
  const float* tm_a2  = (const float*)d_in[8];
  const float* tm_lw  = (const float*)d_in[9];
  const float* tm_lb  = (const float*)d_in[10];
  const float* tm_g   = (const float*)d_in[11];
  const float* tm_b   = (const float*)d_in[12];
  const float* fm_W   = (const float*)d_in[13];
  const float* fm_a1  = (const float*)d_in[14];
  const float* fm_a2  = (const float*)d_in[15];
  const float* fm_lw  = (const float*)d_in[16];
  const float* fm_lb  = (const float*)d_in[17];
  const float* fm_g   = (const float*)d_in[18];
  const float* fm_b   = (const float*)d_in[19];
  const float* c_w1   = (const float*)d_in[20];
  const float* c_b1   = (const float*)d_in[21];
  const float* c_w2   = (const float*)d_in[22];
  const float* c_b2   = (const float*)d_in[23];
  float* out = (float*)d_out;

  // workspace carve-up (~190 MB)
  short* axb    = (short*)d_ws;                  // 25,690,112 bf16 (row-major)
  short* tmpb   = axb + 25690112;                // 25,690,112 bf16 (row-major)
  float* xtm    = (float*)(tmpb + 25690112);     // 131,072 f
  short* xvb    = (short*)(xtm + 131072);        // 131,072 bf16
  short* tmptmb = xvb + 131072;                  // 131,072 bf16
  short* WTb_fm = tmptmb + 131072;               // 262,144 bf16 (fragment order)
  short* WTb_tm = WTb_fm + 262144;               // 262,144 bf16
  short* LWb_fm = WTb_tm + 262144;               // 262,144 bf16
  short* LWb_tm = LWb_fm + 262144;               // 262,144 bf16
  short* pwf_hi = LWb_tm + 262144;               // 393,216 bf16 (fragment order)
  short* pwf_lo = pwf_hi + 393216;               // 393,216 bf16
  unsigned long long* sel_fm = (unsigned long long*)(pwf_lo + 393216); // 784
  unsigned long long* sel_tm = sel_fm + 784;                           // 4
  double* sums  = (double*)(sel_tm + 4);         // 50,176 f64
  float* gp     = (float*)(sums + 50176);        // 512 f
  float* cst    = gp + 512;                      // 2 f
  short* fmh = (short*)(cst + 2);                // 20,447,232 shorts
  short* fml = fmh + 20447232;                   // 20,447,232 shorts

  // 0) zero topk partial sums
  hipMemsetAsync(sums, 0, (size_t)NG_FM * TT * sizeof(double), stream);

  // 1) weight preps (fragment order) + x_v bf16 + gp table
  k_prepPW2<<<192, 256, 0, stream>>>(pre_w, pwf_hi, pwf_lo);
  k_prepWb2<<<128, 256, 0, stream>>>(fm_W, WTb_fm);
  k_prepWb2<<<128, 256, 0, stream>>>(tm_W, WTb_tm);
  k_prepLWb2<<<128, 256, 0, stream>>>(fm_lw, LWb_fm);
  k_prepLWb2<<<128, 256, 0, stream>>>(tm_lw, LWb_tm);
  k_cvt<<<512, 256, 0, stream>>>(x_v, xvb);
  k_prepGP<<<1, 256, 0, stream>>>(fm_g, fm_b, post_w, post_b, gp, cst);

  // 2) pre head conv in two image-halves (axb bf16 + norm partials only)
  for (int half = 0; half < 2; half++) {
    k_prepFM3<<<dim3(12, 128), 256, 0, stream>>>(fmap, fmh, fml, half * 128);
    k_preconv3<<<1024, 256, 0, stream>>>(fmh, fml, pwf_hi, pwf_lo, pre_b, axb, sums, half * 128);
  }

  // 3) top-k selection bitmasks
  k_topk2<<<NG_FM, 64, 0, stream>>>(sums, sel_fm);
  k_topk<<<4, 64, 0, stream>>>(x_v, sel_tm);

  // 4) h = x @ Wcat  (FM: barrier-free block-per-half-graph; TM: tiny k_gemm)
  k_gemm1g<<<1568, 256, 0, stream>>>(axb, WTb_fm, tmpb);
  k_gemm<<<8, 256, 0, stream>>>(xvb, WTb_tm, nullptr, nullptr, nullptr, tmptmb, 2, 0);

  // 5) fused attention (MFMA PV, bf16 in-place)
  k_attn<<<dim3(NHEAD, NG_FM), 256, 0, stream>>>(tmpb, fm_a1, fm_a2, sel_fm);
  k_attn<<<dim3(NHEAD, 4), 256, 0, stream>>>(tmptmb, tm_a1, tm_a2, sel_tm);

  // 6) FM: FUSED gemm2 + LN + post conv -> ano_map (residual = bf16 axb)
  k_gemm2ln<<<1568, 256, 0, stream>>>(tmpb, LWb_fm, fm_lb, axb, gp, cst, out + 256);
  //    TM: gemm2 with residual from x_v -> xtm f32
  k_gemm<<<8, 256, 0, stream>>>(tmptmb, LWb_tm, tm_lb, x_v, xtm, nullptr, 2, 0);

  // 7) TM: LN in-place
  k_ln<<<NIMG, 64, 0, stream>>>(xtm, tm_g, tm_b);

  // 8) classifier -> logits
  k_cls<<<NIMG, 256, 0, stream>>>(xtm, c_w1, c_b1, c_w2, c_b2, out);
}

// Round 21
// 553.047 us; speedup vs baseline: 1.1982x; 1.1982x over previous
//
#include <hip/hip_runtime.h>
#include <cstdint>
#include <cstddef>

// Model dims
constexpr int TT   = 64;    // T
constexpr int DD   = 512;   // D
constexpr int NHEAD= 8;
constexpr int DHH  = 64;
constexpr int NPIX = 196;   // 14*14
constexpr int CIN  = 768;
constexpr int KSEL = 44;    // int(0.7*64)
constexpr int NG_FM= 784;   // B*N
constexpr int NIMG = 256;   // B*T
// distance_adj underflow band: exp(-|0.6*d^2+0.2|) in fp32.
// d=12 -> 2.4e-38 (normal). d=13 -> subnormal -> flushed (FTZ). d>=14 -> 0.
constexpr int DBAND = 12;

typedef __attribute__((ext_vector_type(8))) short bf16x8;
typedef __attribute__((ext_vector_type(4))) float f32x4;

__device__ __forceinline__ short bfr(float x) {
  union { float f; unsigned u; } v; v.f = x;
  unsigned r = (v.u + 0x7fffu + ((v.u >> 16) & 1u)) >> 16;   // RNE
  return (short)r;
}
__device__ __forceinline__ float bf2f(short s) {
  return __uint_as_float(((unsigned)(unsigned short)s) << 16);
}

// ---------------------------------------------------------------------------
// prep: pre_w (f32 [o][k], k=768) -> bf16 hi/lo in MFMA FRAGMENT order.
// ---------------------------------------------------------------------------
__global__ void k_prepPW2(const float* __restrict__ pw, short* __restrict__ hi,
                          short* __restrict__ lo)
{
  int m = blockIdx.x * 256 + threadIdx.x;            // < 512*96
  int o = m / 96, kc = m - o * 96;
  int mt = o >> 6, ot = (o >> 4) & 3, lr = o & 15;
  int ks = kc >> 2, lg = kc & 3;
  size_t addr = ((((size_t)(mt * 4 + ot) * 24 + ks) * 64 + lg * 16 + lr)) * 8;
  const float* src = pw + (size_t)o * CIN + kc * 8;
  #pragma unroll
  for (int j = 0; j < 8; j++) {
    float x = src[j];
    unsigned u = __float_as_uint(x);
    hi[addr + j] = (short)(u >> 16);
    lo[addr + j] = bfr(x - __uint_as_float(u & 0xffff0000u));
  }
}

// ---------------------------------------------------------------------------
// prep: fmap [n][c][hw] f32 -> bf16 hi/lo FRAGMENT order (half-batch).
// ---------------------------------------------------------------------------
__global__ __launch_bounds__(256) void k_prepFM3(
    const float* __restrict__ fmap, short* __restrict__ fh,
    short* __restrict__ fl, int n0)
{
  __shared__ float ar[64][197];                      // pitch 197
  const int cc = blockIdx.x;                         // 12 chunks of 64 ch
  const int nl = blockIdx.y;                         // 0..127
  const int tid = threadIdx.x;
  const float* src = fmap + ((size_t)(n0 + nl) * CIN + cc * 64) * NPIX;
  for (int i = tid; i < 64 * 49; i += 256) {
    int c = i / 49, q = i - c * 49;
    float4 v = *(const float4*)&src[(size_t)c * NPIX + q * 4];
    *(float4*)&ar[c][q * 4] = v;
  }
  __syncthreads();
  for (int i = tid; i < 208 * 8; i += 256) {
    int hw = i >> 3, kc = i & 7;
    int ks = cc * 2 + (kc >> 2), lg = kc & 3;
    size_t addr = ((((size_t)nl * 13 + (hw >> 4)) * 24 + ks) * 64 + lg * 16 + (hw & 15)) * 8;
    union { short s[8]; bf16x8 v; } hh, ll;
    #pragma unroll
    for (int j = 0; j < 8; j++) {
      float x = (hw < NPIX) ? ar[kc * 8 + j][hw] : 0.f;
      unsigned u = __float_as_uint(x);
      hh.s[j] = (short)(u >> 16);
      ll.s[j] = bfr(x - __uint_as_float(u & 0xffff0000u));
    }
    *(bf16x8*)&fh[addr] = hh.v;
    *(bf16x8*)&fl[addr] = ll.v;
  }
}

// ---------------------------------------------------------------------------
// K1: pre head 1x1 conv (768->512) + bias + ReLU via split-bf16 MFMA.
// B (fm) fragments prefetched ONE K-step ahead into a register ping-pong.
// ---------------------------------------------------------------------------
__global__ __launch_bounds__(256) void k_preconv3(
    const short* __restrict__ fmfh, const short* __restrict__ fmfl,
    const short* __restrict__ pwfh, const short* __restrict__ pwfl,
    const float* __restrict__ pb, short* __restrict__ axb,
    double* __restrict__ sums, int n0)
{
  __shared__ float arena[7616];                      // epilogue only
  const int wg = blockIdx.x;                         // 1024 (128 imgs)
  const int mt = (wg >> 3) & 7;                      // o-chunk
  const int nl = (wg & 7) | ((wg >> 6) << 3);        // local image (XCD-group)
  const int n  = n0 + nl;
  const int b  = n >> 6, t = n & 63;
  const int tid = threadIdx.x;
  const int w = tid >> 6, l = tid & 63;
  const int lr = l & 15, lg = l >> 4;
  const int o0 = mt * 64;

  const int hwt0 = (w == 0) ? 0 : 1 + 3 * w;         // waves: 4,3,3,3 hw-tiles
  const int nq   = (w == 0) ? 4 : 3;

  const short* fbh = fmfh + ((size_t)nl * 13 + hwt0) * 12288 + l * 8;
  const short* fbl = fmfl + ((size_t)nl * 13 + hwt0) * 12288 + l * 8;
  const short* pwh = pwfh + (size_t)(mt * 4) * 12288 + l * 8;
  const short* pwl = pwfl + (size_t)(mt * 4) * 12288 + l * 8;

  f32x4 acc[4][4];                                   // [q][ot]
  #pragma unroll
  for (int q = 0; q < 4; q++)
    #pragma unroll
    for (int ot = 0; ot < 4; ot++) acc[q][ot] = (f32x4){0.f, 0.f, 0.f, 0.f};

  bf16x8 BhA[4], BlA[4], BhB[4], BlB[4];
  #pragma unroll
  for (int q = 0; q < 4; q++) if (q < nq) {          // preload ks=0 -> set A
    BhA[q] = *(const bf16x8*)&fbh[(size_t)q * 12288];
    BlA[q] = *(const bf16x8*)&fbl[(size_t)q * 12288];
  }

  for (int kp = 0; kp < 12; kp++) {
    const int ks0 = kp * 2;
    #pragma unroll
    for (int q = 0; q < 4; q++) if (q < nq) {
      BhB[q] = *(const bf16x8*)&fbh[(size_t)q * 12288 + (ks0 + 1) * 512];
      BlB[q] = *(const bf16x8*)&fbl[(size_t)q * 12288 + (ks0 + 1) * 512];
    }
    {
      bf16x8 Ah[4], Al[4];
      #pragma unroll
      for (int ot = 0; ot < 4; ot++) {
        Ah[ot] = *(const bf16x8*)&pwh[(size_t)ot * 12288 + ks0 * 512];
        Al[ot] = *(const bf16x8*)&pwl[(size_t)ot * 12288 + ks0 * 512];
      }
      #pragma unroll
      for (int q = 0; q < 4; q++) if (q < nq) {
        #pragma unroll
        for (int ot = 0; ot < 4; ot++) {
          acc[q][ot] = __builtin_amdgcn_mfma_f32_16x16x32_bf16(Al[ot], BhA[q], acc[q][ot], 0, 0, 0);
          acc[q][ot] = __builtin_amdgcn_mfma_f32_16x16x32_bf16(Ah[ot], BlA[q], acc[q][ot], 0, 0, 0);
          acc[q][ot] = __builtin_amdgcn_mfma_f32_16x16x32_bf16(Ah[ot], BhA[q], acc[q][ot], 0, 0, 0);
        }
      }
    }
    if (kp < 11) {
      #pragma unroll
      for (int q = 0; q < 4; q++) if (q < nq) {
        BhA[q] = *(const bf16x8*)&fbh[(size_t)q * 12288 + (ks0 + 2) * 512];
        BlA[q] = *(const bf16x8*)&fbl[(size_t)q * 12288 + (ks0 + 2) * 512];
      }
    }
    {
      bf16x8 Ah[4], Al[4];
      #pragma unroll
      for (int ot = 0; ot < 4; ot++) {
        Ah[ot] = *(const bf16x8*)&pwh[(size_t)ot * 12288 + (ks0 + 1) * 512];
        Al[ot] = *(const bf16x8*)&pwl[(size_t)ot * 12288 + (ks0 + 1) * 512];
      }
      #pragma unroll
      for (int q = 0; q < 4; q++) if (q < nq) {
        #pragma unroll
        for (int ot = 0; ot < 4; ot++) {
          acc[q][ot] = __builtin_amdgcn_mfma_f32_16x16x32_bf16(Al[ot], BhB[q], acc[q][ot], 0, 0, 0);
          acc[q][ot] = __builtin_amdgcn_mfma_f32_16x16x32_bf16(Ah[ot], BlB[q], acc[q][ot], 0, 0, 0);
          acc[q][ot] = __builtin_amdgcn_mfma_f32_16x16x32_bf16(Ah[ot], BhB[q], acc[q][ot], 0, 0, 0);
        }
      }
    }
  }

  float4 pbf[4];
  #pragma unroll
  for (int ot = 0; ot < 4; ot++)
    pbf[ot] = *(const float4*)&pb[o0 + ot * 16 + 4 * lg];

  #pragma unroll
  for (int pass = 0; pass < 2; pass++) {
    const int tbase = pass ? 7 : 0;
    const int tend  = pass ? 13 : 7;
    const int rbase = tbase * 16;
    const int rows  = (tend - tbase) * 16;
    __syncthreads();
    #pragma unroll
    for (int q = 0; q < 4; q++) if (q < nq) {
      int hwt = hwt0 + q;
      if (hwt >= tbase && hwt < tend) {
        int row_l = hwt * 16 + lr - rbase;
        #pragma unroll
        for (int ot = 0; ot < 4; ot++) {
          int col = (ot * 16 + 4 * lg + 4 * row_l) % 68;   // skew: conflict-free
          f32x4 a = acc[q][ot];
          float4 o4v;
          o4v.x = fmaxf(a[0] + pbf[ot].x, 0.f);
          o4v.y = fmaxf(a[1] + pbf[ot].y, 0.f);
          o4v.z = fmaxf(a[2] + pbf[ot].z, 0.f);
          o4v.w = fmaxf(a[3] + pbf[ot].w, 0.f);
          *(float4*)&arena[row_l * 68 + col] = o4v;
        }
      }
    }
    __syncthreads();
    for (int i = tid; i < rows * 16; i += 256) {      // trip uniform
      int row_l = i >> 4, o4 = i & 15;
      int hw = rbase + row_l;
      float4 v = make_float4(0.f, 0.f, 0.f, 0.f);
      if (hw < NPIX) {
        int col = (o4 * 4 + 4 * row_l) % 68;
        v = *(const float4*)&arena[row_l * 68 + col];
        size_t idx = ((size_t)(b * NPIX + hw) * TT + t) * DD + o0 + o4 * 4;
        *(short4*)&axb[idx] = make_short4(bfr(v.x), bfr(v.y), bfr(v.z), bfr(v.w));
      }
      double vs = (double)v.x * v.x + (double)v.y * v.y
                + (double)v.z * v.z + (double)v.w * v.w;
      vs += __shfl_xor(vs, 1); vs += __shfl_xor(vs, 2);
      vs += __shfl_xor(vs, 4); vs += __shfl_xor(vs, 8);
      if ((i & 15) == 0 && hw < NPIX)
        atomicAdd(&sums[(size_t)(b * NPIX + hw) * TT + t], vs);
    }
  }
}

// ---------------------------------------------------------------------------
// GEMM B-operand preps -> bf16 FRAGMENT order.
// ---------------------------------------------------------------------------
__global__ void k_prepWb2(const float* __restrict__ W, short* __restrict__ o)
{
  int m = blockIdx.x * 256 + threadIdx.x;            // < 512*64
  int j = m >> 6, kc = m & 63;
  int ks = kc >> 2, lg = kc & 3;
  size_t addr = (((size_t)(j >> 4) * 16 + ks) * 64 + lg * 16 + (j & 15)) * 8;
  #pragma unroll
  for (int jj = 0; jj < 8; jj++) {
    int k = kc * 8 + jj;
    o[addr + jj] = bfr(W[(size_t)(j >> 6) * (DD * DHH) + (size_t)k * DHH + (j & 63)]);
  }
}

__global__ void k_prepLWb2(const float* __restrict__ a, short* __restrict__ o)
{
  int m = blockIdx.x * 256 + threadIdx.x;            // < 512*64
  int j = m >> 6, kc = m & 63;
  int ks = kc >> 2, lg = kc & 3;
  size_t addr = (((size_t)(j >> 4) * 16 + ks) * 64 + lg * 16 + (j & 15)) * 8;
  const float* src = a + (size_t)j * DD + kc * 8;
  #pragma unroll
  for (int jj = 0; jj < 8; jj++) o[addr + jj] = bfr(src[jj]);
}

__global__ void k_cvt(const float* __restrict__ a, short* __restrict__ o)
{
  int m = blockIdx.x * 256 + threadIdx.x;
  o[m] = bfr(a[m]);
}

// gp = ln_g * post_w; cst[0] = sum(gp); cst[1] = sum(ln_b*post_w) + post_b
__global__ void k_prepGP(const float* __restrict__ g, const float* __restrict__ b,
                         const float* __restrict__ pw, const float* __restrict__ pb,
                         float* __restrict__ gp, float* __restrict__ cst)
{
  __shared__ float red[256], red2[256];
  int tid = threadIdx.x;
  float s1 = 0.f, s2 = 0.f;
  for (int c = tid; c < 512; c += 256) {
    float gpv = g[c] * pw[c];
    gp[c] = gpv;
    s1 += gpv;
    s2 += b[c] * pw[c];
  }
  red[tid] = s1; red2[tid] = s2;
  __syncthreads();
  for (int s = 128; s > 0; s >>= 1) {
    if (tid < s) { red[tid] += red[tid + s]; red2[tid] += red2[tid + s]; }
    __syncthreads();
  }
  if (tid == 0) { cst[0] = red[0]; cst[1] = red2[0] + pb[0]; }
}

// ---------------------------------------------------------------------------
// K2a/K2b: top-k selection bitmasks (fp64 ranking).
// ---------------------------------------------------------------------------
__global__ void k_topk(const float* __restrict__ x, unsigned long long* __restrict__ sel)
{
  int g = blockIdx.x, lane = threadIdx.x;            // 64 threads
  const float* row = x + ((size_t)g * TT + lane) * DD;
  double s = 0.0;
  for (int dd = 0; dd < DD; dd += 4) {
    float4 v = *(const float4*)(row + dd);
    s += (double)v.x * (double)v.x + (double)v.y * (double)v.y
       + (double)v.z * (double)v.z + (double)v.w * (double)v.w;
  }
  __shared__ double mag[64];
  mag[lane] = s;
  __syncthreads();
  int rank = 0;
  for (int j = 0; j < 64; j++) {
    double m = mag[j];
    rank += (m > s) || (m == s && j < lane);
  }
  unsigned long long bal = __ballot(rank < KSEL);
  if (lane == 0) sel[g] = bal;
}

__global__ void k_topk2(const double* __restrict__ sums, unsigned long long* __restrict__ sel)
{
  int g = blockIdx.x, lane = threadIdx.x;
  double s = sums[(size_t)g * TT + lane];
  __shared__ double mag[64];
  mag[lane] = s;
  __syncthreads();
  int rank = 0;
  for (int j = 0; j < 64; j++) {
    double m = mag[j];
    rank += (m > s) || (m == s && j < lane);
  }
  unsigned long long bal = __ballot(rank < KSEL);
  if (lane == 0) sel[g] = bal;
}

// ---------------------------------------------------------------------------
// K3a: flat GEMM (round-10/13 proven structure) — used for gemm1-FM and the
// tiny TM launches. Measured <=86us for the FM launch by round 19.
// ---------------------------------------------------------------------------
__global__ __launch_bounds__(256) void k_gemm(
    const short* __restrict__ Ab, const short* __restrict__ Bbf,
    const float* __restrict__ bias, const float* __restrict__ Res,
    float* __restrict__ Outf, short* __restrict__ Outb,
    int Mtiles, int swz)
{
  __shared__ short Asl[2][128 * 40];
  const int wg = blockIdx.x;
  int mt, nt;
  if (swz) { int xcd = wg & 7, idx = wg >> 3; mt = xcd * (Mtiles >> 3) + (idx >> 2); nt = idx & 3; }
  else     { mt = wg >> 2; nt = wg & 3; }
  const int m0 = mt * 128, n0 = nt * 128;
  const int tid = threadIdx.x;
  const int l  = tid & 63;
  const int lr = l & 15, lg = l >> 4;
  const int wm = (tid >> 7) & 1, wn = (tid >> 6) & 1;

  const int srow = tid >> 1, skq = tid & 1;
  const short* gA = Ab + (size_t)(m0 + srow) * DD + skq * 16;
  const int soff = srow * 40 + skq * 16;

  bf16x8 ra0 = *(const bf16x8*)(gA);
  bf16x8 ra1 = *(const bf16x8*)(gA + 8);
  *(bf16x8*)&Asl[0][soff]     = ra0;
  *(bf16x8*)&Asl[0][soff + 8] = ra1;
  __syncthreads();

  f32x4 acc[4][4] = {};
  for (int ks = 0; ks < 16; ks++) {
    const int cur = ks & 1;
    if (ks < 15) {
      const int k0 = (ks + 1) * 32;
      ra0 = *(const bf16x8*)(gA + k0);
      ra1 = *(const bf16x8*)(gA + k0 + 8);
    }
    bf16x8 af[4], bfv[4];
    #pragma unroll
    for (int mi = 0; mi < 4; mi++)
      af[mi] = *(const bf16x8*)&Asl[cur][(wm * 64 + mi * 16 + lr) * 40 + lg * 8];
    #pragma unroll
    for (int ni = 0; ni < 4; ni++) {
      size_t boff = (((size_t)(nt * 8 + wn * 4 + ni) * 16 + ks) * 64 + l) * 8;
      bfv[ni] = *(const bf16x8*)&Bbf[boff];
    }
    #pragma unroll
    for (int mi = 0; mi < 4; mi++)
      #pragma unroll
      for (int ni = 0; ni < 4; ni++)
        acc[mi][ni] = __builtin_amdgcn_mfma_f32_16x16x32_bf16(af[mi], bfv[ni], acc[mi][ni], 0, 0, 0);
    if (ks < 15) {
      *(bf16x8*)&Asl[cur ^ 1][soff]     = ra0;
      *(bf16x8*)&Asl[cur ^ 1][soff + 8] = ra1;
      __syncthreads();
    }
  }

  #pragma unroll
  for (int mi = 0; mi < 4; mi++) {
    #pragma unroll
    for (int r = 0; r < 4; r++) {
      const size_t row = (size_t)(m0 + wm * 64 + mi * 16 + lg * 4 + r);
      #pragma unroll
      for (int ni = 0; ni < 4; ni++) {
        const int col = n0 + wn * 64 + ni * 16 + lr;
        float v = acc[mi][ni][r];
        if (bias) v += bias[col];
        if (Res)  v += Res[row * DD + col];
        if (Outf) Outf[row * DD + col] = v;
        if (Outb) Outb[row * DD + col] = bfr(v);
      }
    }
  }
}

// ---------------------------------------------------------------------------
// K4-FM: FUSED gemm2 + LayerNorm + post-conv (round-17: 2 blocks/graph).
// ---------------------------------------------------------------------------
__global__ __launch_bounds__(256) void k_gemm2ln(
    const short* __restrict__ Ab, const short* __restrict__ Bbf,
    const float* __restrict__ bias, const short* __restrict__ Resb,
    const float* __restrict__ gp, const float* __restrict__ cst,
    float* __restrict__ outp)
{
  __shared__ short Asl[32 * 520];                    // 33,280 B
  __shared__ float red[2][32][3];                    // 768 B
  const int wg = blockIdx.x;                         // 1568
  const int xcd = wg & 7, idx = wg >> 3;             // idx 0..195
  const int g = xcd * 98 + (idx >> 1);               // graph (XCD-grouped)
  const int half = idx & 1;
  const int m0 = g * 64 + half * 32;
  const int tid = threadIdx.x;
  const int w = tid >> 6, l = tid & 63;
  const int lr = l & 15, lg = l >> 4;
  const int rowb = (w & 1) * 16;
  const int ch  = w >> 1;                            // col half
  const int ntb = ch * 16;

  #pragma unroll
  for (int i = 0; i < 8; i++) {
    int c = tid + i * 256;                           // < 2048 chunks of 8
    int row = c >> 6, off = (c & 63) * 8;
    *(bf16x8*)&Asl[row * 520 + off] =
        *(const bf16x8*)&Ab[(size_t)(m0 + row) * DD + off];
  }
  __syncthreads();

  f32x4 acc[16];
  #pragma unroll
  for (int i = 0; i < 16; i++) acc[i] = (f32x4){0.f, 0.f, 0.f, 0.f};

  for (int ks = 0; ks < 16; ks++) {
    bf16x8 af = *(const bf16x8*)&Asl[(rowb + lr) * 520 + ks * 32 + lg * 8];
    #pragma unroll
    for (int ntl = 0; ntl < 16; ntl++) {
      bf16x8 bb = *(const bf16x8*)&Bbf[(((size_t)(ntb + ntl) * 16 + ks) * 64 + l) * 8];
      acc[ntl] = __builtin_amdgcn_mfma_f32_16x16x32_bf16(af, bb, acc[ntl], 0, 0, 0);
    }
  }

  float sum[4] = {0.f,0.f,0.f,0.f}, sumsq[4] = {0.f,0.f,0.f,0.f}, dgp[4] = {0.f,0.f,0.f,0.f};
  #pragma unroll
  for (int ntl = 0; ntl < 16; ntl++) {
    int col = (ntb + ntl) * 16 + lr;
    float bi  = bias[col];
    float gpv = gp[col];
    #pragma unroll
    for (int r = 0; r < 4; r++) {
      size_t row = (size_t)(m0 + rowb + lg * 4 + r);
      float v = acc[ntl][r] + bi + bf2f(Resb[row * DD + col]);
      sum[r] += v; sumsq[r] += v * v; dgp[r] += v * gpv;
    }
  }
  #pragma unroll
  for (int r = 0; r < 4; r++) {
    #pragma unroll
    for (int mof = 1; mof <= 8; mof <<= 1) {
      sum[r]   += __shfl_xor(sum[r], mof);
      sumsq[r] += __shfl_xor(sumsq[r], mof);
      dgp[r]   += __shfl_xor(dgp[r], mof);
    }
    if (lr == 0) {
      int rl = rowb + lg * 4 + r;                    // 0..31
      red[ch][rl][0] = sum[r]; red[ch][rl][1] = sumsq[r]; red[ch][rl][2] = dgp[r];
    }
  }
  __syncthreads();
  if (tid < 32) {
    float S = red[0][tid][0] + red[1][tid][0];
    float Q = red[0][tid][1] + red[1][tid][1];
    float D = red[0][tid][2] + red[1][tid][2];
    float mean = S * (1.f / 512.f);
    float var  = Q * (1.f / 512.f) - mean * mean;
    float rstd = rsqrtf(var + 1e-5f);
    const int b = g / NPIX, hw = g - b * NPIX;
    const int t = half * 32 + tid;
    outp[(size_t)b * (TT * NPIX) + t * NPIX + hw] = rstd * (D - mean * cst[0]) + cst[1];
  }
}

// ---------------------------------------------------------------------------
// K3b: fused GAT attention per (head, graph); h bf16 row-major, in-place.
// PV product via MFMA (round-18 structure).
// ---------------------------------------------------------------------------
__global__ __launch_bounds__(256) void k_attn(
    short* __restrict__ tmp, const float* __restrict__ a1v,
    const float* __restrict__ a2v, const unsigned long long* __restrict__ sel)
{
  __shared__ short hb[4096];                         // B-frags: [ct*2+ks][64][8]
  __shared__ short attnb[64 * 72];                   // A-frags: P bf16, pitch 72
  __shared__ float s1[64], s2[64], aw[128], cnorm[64];
  __shared__ float redc[4][4][16];                   // [wave][ct][lr]
  const int h = blockIdx.x, g = blockIdx.y;
  const int tid = threadIdx.x;
  const int w = tid >> 6, l = tid & 63;
  const int lr = l & 15, lg = l >> 4;
  short* base = tmp + (size_t)g * TT * DD + h * DHH;

  if (tid < 128) aw[tid] = (tid < 64) ? a1v[h * 64 + tid] : a2v[h * 64 + (tid - 64)];
  __syncthreads();

  #pragma unroll
  for (int p = 0; p < 2; p++) {
    int c = tid + p * 256;                           // 0..511
    int t = c >> 3, k8 = c & 7;                      // row t, col chunk
    bf16x8 v = *(const bf16x8*)&base[(size_t)t * DD + k8 * 8];
    const int ct = k8 >> 1;                          // col tile
    const int ks = t >> 5, lgk = (t >> 3) & 3, jj = t & 7;
    const int cbase = ((ct * 2 + ks) * 64 + lgk * 16 + (k8 & 1) * 8) * 8 + jj;
    float v1 = 0.f, v2 = 0.f;
    #pragma unroll
    for (int j = 0; j < 8; j++) {
      float x = bf2f(v[j]);
      int dh = k8 * 8 + j;
      v1 += x * aw[dh];
      v2 += x * aw[64 + dh];
      hb[cbase + j * 8] = v[j];
    }
    v1 += __shfl_xor(v1, 1); v1 += __shfl_xor(v1, 2); v1 += __shfl_xor(v1, 4);
    v2 += __shfl_xor(v2, 1); v2 += __shfl_xor(v2, 2); v2 += __shfl_xor(v2, 4);
    if (k8 == 0) { s1[t] = v1; s2[t] = v2; }
  }
  __syncthreads();

  const unsigned long long sm = sel[g];
  {
    const int i4 = tid >> 2, sub = tid & 3;
    const bool seli = (sm >> i4) & 1ULL;
    const float vi = s1[i4];
    float ev[16];
    float mx = -1e30f;
    #pragma unroll
    for (int q = 0; q < 16; q++) {
      int j = sub * 16 + q;
      float e = vi + s2[j];
      e = e >= 0.f ? e : 0.2f * e;                   // leaky_relu(0.2)
      int dist = i4 > j ? i4 - j : j - i4;
      bool ok = (seli || ((sm >> j) & 1ULL)) && (dist <= DBAND);
      e = ok ? e : -9e15f;
      ev[q] = e;
      mx = fmaxf(mx, e);
    }
    mx = fmaxf(mx, __shfl_xor(mx, 1));
    mx = fmaxf(mx, __shfl_xor(mx, 2));
    float sum = 0.f;
    #pragma unroll
    for (int q = 0; q < 16; q++) { ev[q] = expf(ev[q] - mx); sum += ev[q]; }
    sum += __shfl_xor(sum, 1); sum += __shfl_xor(sum, 2);
    float inv = 1.f / sum;
    #pragma unroll
    for (int q = 0; q < 16; q++)
      attnb[i4 * 72 + sub * 16 + q] = bfr(ev[q] * inv);
  }
  __syncthreads();

  f32x4 acc[4];
  #pragma unroll
  for (int ct = 0; ct < 4; ct++) acc[ct] = (f32x4){0.f, 0.f, 0.f, 0.f};
  #pragma unroll
  for (int ks = 0; ks < 2; ks++) {
    bf16x8 af = *(const bf16x8*)&attnb[(w * 16 + lr) * 72 + ks * 32 + lg * 8];
    #pragma unroll
    for (int ct = 0; ct < 4; ct++) {
      bf16x8 bb = *(const bf16x8*)&hb[((ct * 2 + ks) * 64 + l) * 8];
      acc[ct] = __builtin_amdgcn_mfma_f32_16x16x32_bf16(af, bb, acc[ct], 0, 0, 0);
    }
  }

  float vv[4][4];
  float cs[4] = {0.f, 0.f, 0.f, 0.f};
  #pragma unroll
  for (int ct = 0; ct < 4; ct++)
    #pragma unroll
    for (int r = 0; r < 4; r++) {
      float v = acc[ct][r];
      v = v > 0.f ? v : expm1f(v);
      v = v >= 0.f ? sqrtf(v) : -sqrtf(-v);
      vv[ct][r] = v;
      cs[ct] += v * v;
    }
  #pragma unroll
  for (int ct = 0; ct < 4; ct++) {
    cs[ct] += __shfl_xor(cs[ct], 16);
    cs[ct] += __shfl_xor(cs[ct], 32);
    if (lg == 0) redc[w][ct][lr] = cs[ct];
  }
  __syncthreads();
  if (tid < 64) {
    int ct = tid >> 4, c = tid & 15;
    float S = redc[0][ct][c] + redc[1][ct][c] + redc[2][ct][c] + redc[3][ct][c];
    cnorm[ct * 16 + c] = fmaxf(sqrtf(S), 1e-12f);
  }
  __syncthreads();
  #pragma unroll
  for (int ct = 0; ct < 4; ct++) {
    float inv = 1.f / cnorm[ct * 16 + lr];
    #pragma unroll
    for (int r = 0; r < 4; r++)
      attnb[(w * 16 + lg * 4 + r) * 72 + ct * 16 + lr] = bfr(vv[ct][r] * inv);
  }
  __syncthreads();
  #pragma unroll
  for (int p = 0; p < 2; p++) {
    int c = tid + p * 256;
    int t = c >> 3, k8 = c & 7;
    *(bf16x8*)&base[(size_t)t * DD + k8 * 8] =
        *(const bf16x8*)&attnb[t * 72 + k8 * 8];
  }
}

// ---------------------------------------------------------------------------
// K5: LayerNorm in-place (TM path), one wave per 512-row.
// ---------------------------------------------------------------------------
__global__ void k_ln(float* __restrict__ x, const float* __restrict__ gam, const float* __restrict__ bet)
{
  const size_t row = blockIdx.x;
  const int lane = threadIdx.x;
  float* p = x + row * DD + lane * 8;
  float4 v0 = *(float4*)p;
  float4 v1 = *(float4*)(p + 4);
  float va[8] = {v0.x, v0.y, v0.z, v0.w, v1.x, v1.y, v1.z, v1.w};
  float s = 0.f;
  #pragma unroll
  for (int i = 0; i < 8; i++) s += va[i];
  #pragma unroll
  for (int m = 32; m >= 1; m >>= 1) s += __shfl_xor(s, m);
  float mean = s * (1.f / 512.f);
  float q = 0.f;
  #pragma unroll
  for (int i = 0; i < 8; i++) { float d = va[i] - mean; q += d * d; }
  #pragma unroll
  for (int m = 32; m >= 1; m >>= 1) q += __shfl_xor(q, m);
  float rstd = rsqrtf(q * (1.f / 512.f) + 1e-5f);
  const float* gp = gam + lane * 8;
  const float* bp = bet + lane * 8;
  float4 g0 = *(const float4*)gp, g1 = *(const float4*)(gp + 4);
  float4 b0 = *(const float4*)bp, b1 = *(const float4*)(bp + 4);
  float ga[8] = {g0.x, g0.y, g0.z, g0.w, g1.x, g1.y, g1.z, g1.w};
  float ba[8] = {b0.x, b0.y, b0.z, b0.w, b1.x, b1.y, b1.z, b1.w};
  float o[8];
  #pragma unroll
  for (int i = 0; i < 8; i++) o[i] = (va[i] - mean) * rstd * ga[i] + ba[i];
  *(float4*)p       = make_float4(o[0], o[1], o[2], o[3]);
  *(float4*)(p + 4) = make_float4(o[4], o[5], o[6], o[7]);
}

// ---------------------------------------------------------------------------
// K7: classifier Conv1d(512->512)+GELU(exact)+Conv1d(512->1), one block per (b,t).
// ---------------------------------------------------------------------------
__global__ __launch_bounds__(256) void k_cls(
    const float* __restrict__ xv, const float* __restrict__ w1,
    const float* __restrict__ b1, const float* __restrict__ w2,
    const float* __restrict__ b2, float* __restrict__ outp)
{
  const int m = blockIdx.x;                          // b*64+t
  const int tid = threadIdx.x;
  __shared__ float xr[512];
  __shared__ float red[256];
  xr[tid] = xv[(size_t)m * DD + tid];
  xr[tid + 256] = xv[(size_t)m * DD + tid + 256];
  __syncthreads();
  float part = 0.f;
  for (int o = tid; o < 512; o += 256) {
    const float* wr = w1 + (size_t)o * DD;
    float d = 0.f;
    for (int cc = 0; cc < DD; cc += 4) {
      float4 wv = *(const float4*)(wr + cc);
      d += wv.x * xr[cc] + wv.y * xr[cc + 1] + wv.z * xr[cc + 2] + wv.w * xr[cc + 3];
    }
    d += b1[o];
    float ge = 0.5f * d * (1.0f + erff(d * 0.70710678118654752f));
    part += ge * w2[o];
  }
  red[tid] = part;
  __syncthreads();
  for (int s = 128; s > 0; s >>= 1) {
    if (tid < s) red[tid] += red[tid + s];
    __syncthreads();
  }
  if (tid == 0) outp[m] = red[0] + b2[0];
}

// ---------------------------------------------------------------------------
extern "C" void kernel_launch(void* const* d_in, const int* in_sizes, int n_in,
                              void* d_out, int out_size, void* d_ws, size_t ws_size,
                              hipStream_t stream)
{
  const float* x_v    = (const float*)d_in[0];
  const float* fmap   = (const float*)d_in[1];
  const float* pre_w  = (const float*)d_in[2];
  const float* pre_b  = (const float*)d_in[3];
  const float* post_w = (const float*)d_in[4];
  const float* post_b = (const float*)d_in[5];
  const float* tm_W   = (const float*)d_in[6];
  const float* tm_a1  = (const float*)d_in[7];
  const float* tm_a2  = (const float*)d_in[8];
  const float* tm_lw  = (const float*)d_in[9];
  const float* tm_lb  = (const float*)d_in[10];
  const float* tm_g   = (const float*)d_in[11];
  const float* tm_b   = (const float*)d_in[12];
  const float* fm_W   = (const float*)d_in[13];
  const float* fm_a1  = (const float*)d_in[14];
  const float* fm_a2  = (const float*)d_in[15];
  const float* fm_lw  = (const float*)d_in[16];
  const float* fm_lb  = (const float*)d_in[17];
  const float* fm_g   = (const float*)d_in[18];
  const float* fm_b   = (const float*)d_in[19];
  const float* c_w1   = (const float*)d_in[20];
  const float* c_b1   = (const float*)d_in[21];
  const float* c_w2   = (const float*)d_in[22];
  const float* c_b2   = (const float*)d_in[23];
  float* out = (float*)d_out;

  // workspace carve-up (~190 MB)
  short* axb    = (short*)d_ws;                  // 25,690,112 bf16 (row-major)
  short* tmpb   = axb + 25690112;                // 25,690,112 bf16 (row-major)
  float* xtm    = (float*)(tmpb + 25690112);     // 131,072 f
  short* xvb    = (short*)(xtm + 131072);        // 131,072 bf16
  short* tmptmb = xvb + 131072;                  // 131,072 bf16
  short* WTb_fm = tmptmb + 131072;               // 262,144 bf16 (fragment order)
  short* WTb_tm = WTb_fm + 262144;               // 262,144 bf16
  short* LWb_fm = WTb_tm + 262144;               // 262,144 bf16
  short* LWb_tm = LWb_fm + 262144;               // 262,144 bf16
  short* pwf_hi = LWb_tm + 262144;               // 393,216 bf16 (fragment order)
  short* pwf_lo = pwf_hi + 393216;               // 393,216 bf16
  unsigned long long* sel_fm = (unsigned long long*)(pwf_lo + 393216); // 784
  unsigned long long* sel_tm = sel_fm + 784;                           // 4
  double* sums  = (double*)(sel_tm + 4);         // 50,176 f64
  float* gp     = (float*)(sums + 50176);        // 512 f
  float* cst    = gp + 512;                      // 2 f
  short* fmh = (short*)(cst + 2);                // 20,447,232 shorts
  short* fml = fmh + 20447232;                   // 20,447,232 shorts

  // 0) zero topk partial sums
  hipMemsetAsync(sums, 0, (size_t)NG_FM * TT * sizeof(double), stream);

  // 1) weight preps (fragment order) + x_v bf16 + gp table
  k_prepPW2<<<192, 256, 0, stream>>>(pre_w, pwf_hi, pwf_lo);
  k_prepWb2<<<128, 256, 0, stream>>>(fm_W, WTb_fm);
  k_prepWb2<<<128, 256, 0, stream>>>(tm_W, WTb_tm);
  k_prepLWb2<<<128, 256, 0, stream>>>(fm_lw, LWb_fm);
  k_prepLWb2<<<128, 256, 0, stream>>>(tm_lw, LWb_tm);
  k_cvt<<<512, 256, 0, stream>>>(x_v, xvb);
  k_prepGP<<<1, 256, 0, stream>>>(fm_g, fm_b, post_w, post_b, gp, cst);

  // 2) pre head conv in two image-halves (axb bf16 + norm partials only)
  for (int half = 0; half < 2; half++) {
    k_prepFM3<<<dim3(12, 128), 256, 0, stream>>>(fmap, fmh, fml, half * 128);
    k_preconv3<<<1024, 256, 0, stream>>>(fmh, fml, pwf_hi, pwf_lo, pre_b, axb, sums, half * 128);
  }

  // 3) top-k selection bitmasks
  k_topk2<<<NG_FM, 64, 0, stream>>>(sums, sel_fm);
  k_topk<<<4, 64, 0, stream>>>(x_v, sel_tm);

  // 4) h = x @ Wcat  (round-13 GEMM, bf16 out)
  k_gemm<<<1568, 256, 0, stream>>>(axb, WTb_fm, nullptr, nullptr, nullptr, tmpb, 392, 1);
  k_gemm<<<8, 256, 0, stream>>>(xvb, WTb_tm, nullptr, nullptr, nullptr, tmptmb, 2, 0);

  // 5) fused attention (MFMA PV, bf16 in-place)
  k_attn<<<dim3(NHEAD, NG_FM), 256, 0, stream>>>(tmpb, fm_a1, fm_a2, sel_fm);
  k_attn<<<dim3(NHEAD, 4), 256, 0, stream>>>(tmptmb, tm_a1, tm_a2, sel_tm);

  // 6) FM: FUSED gemm2 + LN + post conv -> ano_map (residual = bf16 axb)
  k_gemm2ln<<<1568, 256, 0, stream>>>(tmpb, LWb_fm, fm_lb, axb, gp, cst, out + 256);
  //    TM: gemm2 with residual from x_v -> xtm f32
  k_gemm<<<8, 256, 0, stream>>>(tmptmb, LWb_tm, tm_lb, x_v, xtm, nullptr, 2, 0);

  // 7) TM: LN in-place
  k_ln<<<NIMG, 64, 0, stream>>>(xtm, tm_g, tm_b);

  // 8) classifier -> logits
  k_cls<<<NIMG, 256, 0, stream>>>(xtm, c_w1, c_b1, c_w2, c_b2, out);
}